// Round 20
// baseline (89.060 us; speedup 1.0000x reference)
//
#include <hip/hip_runtime.h>
#include <hip/hip_bf16.h>
#include <math.h>
#include <stdint.h>

// Problem constants
#define T_ROWS 16384
#define D_DIM  4096
#define E_EXP  64
#define TOPK   8

constexpr float W_SCALE   = 64.0f;     // folded into W tiles by wprep
constexpr float INV_SCALE = 1.0f / 64.0f;

constexpr int BM   = 64;               // rows per block
constexpr int BK   = 32;               // k per step
constexpr int KQ   = D_DIM / 4;        // 1024 k per block (split-K = 4)
constexpr int NIT  = KQ / BK;          // 32 iterations
constexpr int ABUF = 8192;             // 64 rows x 8 chunks x 16B
constexpr int BBUF = 8192;             // [hi 4KB | lo 4KB] per 32-k tile
constexpr int B_OFF = 3 * ABUF;        // 24576 (A triple-buffered)
constexpr int LDS_TOT = B_OFF + 2 * BBUF;  // 40960 -> 4 blocks/CU

typedef _Float16 f16x8 __attribute__((ext_vector_type(8)));
typedef __fp16   h16x2 __attribute__((ext_vector_type(2)));
typedef float    f32x4 __attribute__((ext_vector_type(4)));

__device__ __forceinline__ void gll16(const void* g, void* l) {
    __builtin_amdgcn_global_load_lds(
        (const __attribute__((address_space(1))) void*)g,
        (__attribute__((address_space(3))) void*)l, 16, 0, 0);
}
#define WAITV(n) asm volatile("s_waitcnt vmcnt(" #n ")" ::: "memory")
#define SB0()    __builtin_amdgcn_sched_barrier(0)

// ---------------------------------------------------------------------------
// K0: W (f32 [64][4096]) -> per-32k-tile packed hi/lo f16 (scaled by 64).
// Tile t (0..127) = 8KB: [hi: e*64B + c'*16B | lo: +4KB], c' = s ^ (e&3).
// ---------------------------------------------------------------------------
__global__ __launch_bounds__(256) void wprep_kernel(
    const float* __restrict__ W, _Float16* __restrict__ Wt)
{
    const int i  = blockIdx.x * 256 + threadIdx.x;    // 32768 threads, 8 k each
    const int e  = i >> 9;
    const int k8 = i & 511;
    const int k  = k8 << 3;
    const int t  = k >> 5;               // 32-k tile
    const int s  = (k >> 3) & 3;         // octet within tile
    const float4 w0 = *(const float4*)&W[(size_t)e * D_DIM + k];
    const float4 w1 = *(const float4*)&W[(size_t)e * D_DIM + k + 4];
    const float xs[8] = {w0.x, w0.y, w0.z, w0.w, w1.x, w1.y, w1.z, w1.w};
    f16x8 hi, lo;
    #pragma unroll
    for (int j = 0; j < 8; ++j) {
        const float x = xs[j] * W_SCALE;
        const _Float16 hh = (_Float16)x;
        hi[j] = hh;
        lo[j] = (_Float16)(x - (float)hh);
    }
    const size_t o = (size_t)t * 4096 + e * 32 + ((s ^ (e & 3)) << 3); // f16 units
    *(f16x8*)(Wt + o) = hi;
    *(f16x8*)(Wt + o + 2048) = lo;
}

// exact split of f32 into (f16-exact hi via mantissa mask) + lo, packed cvt
__device__ __forceinline__ void cvt8(const float4 x0, const float4 x1,
                                     f16x8& hi, f16x8& lo) {
    const float xs[8] = {x0.x, x0.y, x0.z, x0.w, x1.x, x1.y, x1.z, x1.w};
    float hs[8], ls[8];
    #pragma unroll
    for (int j = 0; j < 8; ++j) {
        hs[j] = __uint_as_float(__float_as_uint(xs[j]) & 0xFFFFE000u);
        ls[j] = xs[j] - hs[j];
    }
    #pragma unroll
    for (int j = 0; j < 4; ++j) {
        const h16x2 ph = __builtin_amdgcn_cvt_pkrtz(hs[2 * j], hs[2 * j + 1]);
        const h16x2 pl = __builtin_amdgcn_cvt_pkrtz(ls[2 * j], ls[2 * j + 1]);
        hi[2 * j] = (_Float16)ph[0]; hi[2 * j + 1] = (_Float16)ph[1];
        lo[2 * j] = (_Float16)pl[0]; lo[2 * j + 1] = (_Float16)pl[1];
    }
}

// ---------------------------------------------------------------------------
// K1: split-K=4 GEMM, BM=64, PRODUCER-CONSUMER wave specialization.
// grid (256, 4) x 320 threads: waves 0..3 = consumers (r15 compute layout),
// wave 4 = producer (issues ALL 16 glls/iter, owns the entire vmcnt FIFO).
// Consumers have ZERO vmem in the loop: pure ds_read -> cvt -> MFMA -> barrier.
// Producer FIFO (= r15's, one wave): entering iter i only A(i+1)'s 8 glls
// outstanding; issue B(i+1)[8], A(i+2)[8]; WAITV(8) forces {A(i+1),B(i+1)},
// leaves A(i+2) in flight across the barrier. Never drains in-loop.
// Barrier count matched across branch: 32 each (1 prologue + 30 loop + 1 tail).
// RAW: tile i forced by producer's WAITV before barrier(i-1); consumers read
// after that barrier. WAR: slot written at iter i held tile i-1, last ds_read
// at iter i-1, closed by barrier(i-1) < producer's issue at iter i.
// ---------------------------------------------------------------------------
__global__ __launch_bounds__(320, 5) void gemm_q_kernel(
    const float* __restrict__ h, const _Float16* __restrict__ Wt,
    float* __restrict__ out)
{
    __shared__ char smb[LDS_TOT];

    const int tid  = threadIdx.x;
    const int wv   = tid >> 6;           // 0..3 consumers, 4 producer
    const int lane = tid & 63;
    const int l15  = lane & 15;
    const int kg   = lane >> 4;          // 0..3
    const int row0 = blockIdx.x * BM;
    const int q    = blockIdx.y;         // k-quarter
    const int kb   = q * KQ;

    int aCur = 0, aNxt = ABUF, aStg = 2 * ABUF;
    #define ROT() { int t_ = aCur; aCur = aNxt; aNxt = aStg; aStg = t_; }

    if (wv == 4) {
        // ================= PRODUCER WAVE =================
        // A: gll j (0..7) covers rows j*8 + (lane>>3); chunk slot lane&7 holds
        // global chunk (lane&7) ^ (row&7); row&7 = lane>>3 (j-invariant).
        // LDS dest linear: j*1024 + lane*16 -> row r at r*128 (= r15 layout).
        const char* gA0 = (const char*)h
            + ((size_t)(row0 + (lane >> 3)) * D_DIM + kb) * 4
            + (((lane & 7) ^ (lane >> 3)) << 4);
        // B: linear copy of pre-swizzled 8KB tiles; quarter q at tile q*32.
        const char* gB0 = (const char*)Wt + (size_t)(q * 32) * 8192 + lane * 16;

        #define P_STAGE_A(t, aAdd)                                            \
            { _Pragma("unroll")                                               \
              for (int j = 0; j < 8; ++j)                                     \
                  gll16(gA0 + (size_t)j * 131072 + (size_t)(t) * 128,         \
                        smb + (aAdd) + j * 1024); }
        #define P_STAGE_B(t, par)                                             \
            { _Pragma("unroll")                                               \
              for (int j = 0; j < 8; ++j)                                     \
                  gll16(gB0 + (size_t)(t) * 8192 + j * 1024,                  \
                        smb + B_OFF + (par) * BBUF + j * 1024); }

        // prologue FIFO: [A0(8) | B0(8) | A1(8)]; WAITV(8) forces A0+B0.
        P_STAGE_A(0, aCur)
        SB0();
        P_STAGE_B(0, 0)
        SB0();
        P_STAGE_A(1, aNxt)
        SB0();
        WAITV(8);
        SB0();
        __builtin_amdgcn_s_barrier();            // barrier #1
        for (int i = 0; i < NIT - 2; ++i) {
            P_STAGE_B(i + 1, (i + 1) & 1)
            SB0();                               // pin FIFO: B(i+1) < A(i+2)
            P_STAGE_A(i + 2, aStg)
            SB0();
            WAITV(8);                            // forces A(i+1)+B(i+1)
            SB0();
            __builtin_amdgcn_s_barrier();        // barriers #2..#31
            ROT();
        }
        P_STAGE_B(NIT - 1, (NIT - 1) & 1)
        SB0();
        WAITV(0);                                // drain A(31)+B(31)
        SB0();
        __builtin_amdgcn_s_barrier();            // barrier #32
        return;
    }

    // ================= CONSUMER WAVES (0..3) =================
    const int wm = wv >> 1;              // m-quarter (within each 32-row half)
    const int we = wv & 1;               // e-half

    // A ds_read offsets: m-frag f -> row f*32 + wm*16 + l15
    int aro[2][2];                       // [f][piece]
    #pragma unroll
    for (int f = 0; f < 2; ++f)
        #pragma unroll
        for (int qq = 0; qq < 2; ++qq)
            aro[f][qq] = (f * 32 + wm * 16 + l15) * 128
                       + (((kg * 2 + qq) ^ (l15 & 7)) << 4);
    // B ds_read offsets: expert e, chunk kg ^ (e&3)
    int bro[2][2];                       // [sel hi/lo][es]
    #pragma unroll
    for (int sel = 0; sel < 2; ++sel)
        #pragma unroll
        for (int es = 0; es < 2; ++es) {
            const int e = we * 32 + es * 16 + l15;
            bro[sel][es] = sel * 4096 + e * 64 + ((kg ^ (e & 3)) << 4);
        }

    f32x4 acc[2][2] = {};                // [f][es]
    float4 av[2][2];                     // [f][piece]
    f16x8 bhf[2], blf[2];                // [es]

    #define DSREAD(aAdd, par)                                                 \
        { _Pragma("unroll")                                                   \
          for (int f = 0; f < 2; ++f) {                                       \
              av[f][0] = *(const float4*)(smb + (aAdd) + aro[f][0]);          \
              av[f][1] = *(const float4*)(smb + (aAdd) + aro[f][1]);          \
          }                                                                   \
          _Pragma("unroll")                                                   \
          for (int es = 0; es < 2; ++es) {                                    \
              bhf[es] = *(const f16x8*)(smb + B_OFF + (par) * BBUF + bro[0][es]); \
              blf[es] = *(const f16x8*)(smb + B_OFF + (par) * BBUF + bro[1][es]); \
          } }

    #define MFMAS()                                                           \
        { f16x8 ah[2], al[2];                                                 \
          cvt8(av[0][0], av[0][1], ah[0], al[0]);                             \
          cvt8(av[1][0], av[1][1], ah[1], al[1]);                             \
          _Pragma("unroll")                                                   \
          for (int f = 0; f < 2; ++f)                                         \
              _Pragma("unroll")                                               \
              for (int es = 0; es < 2; ++es) {                                \
                  acc[f][es] = __builtin_amdgcn_mfma_f32_16x16x32_f16(ah[f], bhf[es], acc[f][es], 0, 0, 0); \
                  acc[f][es] = __builtin_amdgcn_mfma_f32_16x16x32_f16(ah[f], blf[es], acc[f][es], 0, 0, 0); \
                  acc[f][es] = __builtin_amdgcn_mfma_f32_16x16x32_f16(al[f], bhf[es], acc[f][es], 0, 0, 0); \
              } }

    __builtin_amdgcn_s_barrier();                // barrier #1 (tile 0 ready)
    for (int i = 0; i < NIT - 2; ++i) {
        DSREAD(aCur, i & 1)
        __builtin_amdgcn_s_setprio(1);
        MFMAS()
        __builtin_amdgcn_s_setprio(0);
        __builtin_amdgcn_s_barrier();            // barriers #2..#31
        ROT();
    }
    DSREAD(aCur, (NIT - 2) & 1)
    MFMAS()
    __builtin_amdgcn_s_barrier();                // barrier #32 (tile 31 ready)
    ROT();
    DSREAD(aCur, (NIT - 1) & 1)
    MFMAS()

    // ---- write scaled partials to out slot q ----
    float* slot = out + (size_t)q * T_ROWS * E_EXP;
    #pragma unroll
    for (int f = 0; f < 2; ++f)
        #pragma unroll
        for (int es = 0; es < 2; ++es)
            #pragma unroll
            for (int r = 0; r < 4; ++r)
                slot[(size_t)(row0 + f * 32 + wm * 16 + kg * 4 + r) * E_EXP
                     + we * 32 + es * 16 + l15] = acc[f][es][r];
}

// ---------------------------------------------------------------------------
// K2: elementwise-safe epilogue. Each thread reads its 4 quarter-partials
// from the 4 out slots, then overwrites the same 4 addresses with
// mask / probs / logits_clean / logits_sel. One wave per row, lane = expert.
// ---------------------------------------------------------------------------
__global__ __launch_bounds__(256) void epilogue_kernel(
    const float* __restrict__ u, float* __restrict__ out)
{
    const int row  = blockIdx.x * 4 + (threadIdx.x >> 6);
    const int lane = threadIdx.x & 63;
    const size_t te = (size_t)T_ROWS * E_EXP;
    const size_t idx = (size_t)row * E_EXP + lane;

    const float p0 = out[0 * te + idx];
    const float p1 = out[1 * te + idx];
    const float p2 = out[2 * te + idx];
    const float p3 = out[3 * te + idx];
    const float val = (((p0 + p1) + p2) + p3) * INV_SCALE;

    out[2 * te + idx] = val;             // logits_clean

    float m = val;
    #pragma unroll
    for (int off = 32; off; off >>= 1) m = fmaxf(m, __shfl_xor(m, off));
    const float p = expf(val - m);
    float ssum = p;
    #pragma unroll
    for (int off = 32; off; off >>= 1) ssum += __shfl_xor(ssum, off);
    out[1 * te + idx] = p / ssum;        // probs

    const float uv = u[idx];
    const float g = -logf(-logf(uv));
    const float sel = val + g;
    out[3 * te + idx] = sel;             // logits_sel

    // top-8, ties -> lowest lane (= lowest expert, matches lax.top_k)
    float v = sel;
    bool chosen = false;
    #pragma unroll
    for (int itk = 0; itk < TOPK; ++itk) {
        float mv = v;
        #pragma unroll
        for (int off = 32; off; off >>= 1) mv = fmaxf(mv, __shfl_xor(mv, off));
        const unsigned long long b = __ballot(v == mv);
        const int sl = __ffsll((long long)b) - 1;
        if (lane == sl) { chosen = true; v = -INFINITY; }
    }
    out[idx] = chosen ? 1.0f : 0.0f;     // mask
}

// ---------------------------------------------------------------------------
extern "C" void kernel_launch(void* const* d_in, const int* in_sizes, int n_in,
                              void* d_out, int out_size, void* d_ws, size_t ws_size,
                              hipStream_t stream) {
    const float* h = (const float*)d_in[0];
    const float* W = (const float*)d_in[1];
    const float* u = (const float*)d_in[2];
    float* out = (float*)d_out;

    _Float16* Wt = (_Float16*)d_ws;                        // 1 MB packed tiles

    hipLaunchKernelGGL(wprep_kernel, dim3(E_EXP * D_DIM / 8 / 256), dim3(256),
                       0, stream, W, Wt);
    hipLaunchKernelGGL(gemm_q_kernel, dim3(T_ROWS / BM, 4), dim3(320),
                       0, stream, h, Wt, out);
    hipLaunchKernelGGL(epilogue_kernel, dim3(T_ROWS / 4), dim3(256),
                       0, stream, u, out);
}

// Round 21
// 78.717 us; speedup vs baseline: 1.1314x; 1.1314x over previous
//
#include <hip/hip_runtime.h>
#include <hip/hip_bf16.h>
#include <math.h>
#include <stdint.h>

// Problem constants
#define T_ROWS 16384
#define D_DIM  4096
#define E_EXP  64
#define TOPK   8

constexpr float W_SCALE   = 64.0f;     // folded into W tiles by wprep
constexpr float INV_SCALE = 1.0f / 64.0f;

constexpr int BM   = 64;               // rows per block
constexpr int BK   = 32;               // k per step
constexpr int KQ   = D_DIM / 4;        // 1024 k per block (split-K = 4)
constexpr int NIT  = KQ / BK;          // 32 iterations
constexpr int ABUF = 8192;             // 64 rows x 8 chunks x 16B
constexpr int BBUF = 8192;             // [hi 4KB | lo 4KB] per 32-k tile
constexpr int B_OFF = 3 * ABUF;        // 24576 (A triple-buffered)
constexpr int LDS_TOT = B_OFF + 2 * BBUF;  // 40960 -> 4 blocks/CU

typedef _Float16 f16x8 __attribute__((ext_vector_type(8)));
typedef __fp16   h16x2 __attribute__((ext_vector_type(2)));
typedef float    f32x4 __attribute__((ext_vector_type(4)));

__device__ __forceinline__ void gll16(const void* g, void* l) {
    __builtin_amdgcn_global_load_lds(
        (const __attribute__((address_space(1))) void*)g,
        (__attribute__((address_space(3))) void*)l, 16, 0, 0);
}
#define WAITV(n) asm volatile("s_waitcnt vmcnt(" #n ")" ::: "memory")
#define SB0()    __builtin_amdgcn_sched_barrier(0)

// ---------------------------------------------------------------------------
// K0: W (f32 [64][4096]) -> per-32k-tile packed hi/lo f16 (scaled by 64).
// Tile t (0..127) = 8KB: [hi: e*64B + c'*16B | lo: +4KB], c' = s ^ (e&3).
// ---------------------------------------------------------------------------
__global__ __launch_bounds__(256) void wprep_kernel(
    const float* __restrict__ W, _Float16* __restrict__ Wt)
{
    const int i  = blockIdx.x * 256 + threadIdx.x;    // 32768 threads, 8 k each
    const int e  = i >> 9;
    const int k8 = i & 511;
    const int k  = k8 << 3;
    const int t  = k >> 5;               // 32-k tile
    const int s  = (k >> 3) & 3;         // octet within tile
    const float4 w0 = *(const float4*)&W[(size_t)e * D_DIM + k];
    const float4 w1 = *(const float4*)&W[(size_t)e * D_DIM + k + 4];
    const float xs[8] = {w0.x, w0.y, w0.z, w0.w, w1.x, w1.y, w1.z, w1.w};
    f16x8 hi, lo;
    #pragma unroll
    for (int j = 0; j < 8; ++j) {
        const float x = xs[j] * W_SCALE;
        const _Float16 hh = (_Float16)x;
        hi[j] = hh;
        lo[j] = (_Float16)(x - (float)hh);
    }
    const size_t o = (size_t)t * 4096 + e * 32 + ((s ^ (e & 3)) << 3); // f16 units
    *(f16x8*)(Wt + o) = hi;
    *(f16x8*)(Wt + o + 2048) = lo;
}

// exact split of f32 into (f16-exact hi via mantissa mask) + lo, packed cvt
__device__ __forceinline__ void cvt8(const float4 x0, const float4 x1,
                                     f16x8& hi, f16x8& lo) {
    const float xs[8] = {x0.x, x0.y, x0.z, x0.w, x1.x, x1.y, x1.z, x1.w};
    float hs[8], ls[8];
    #pragma unroll
    for (int j = 0; j < 8; ++j) {
        hs[j] = __uint_as_float(__float_as_uint(xs[j]) & 0xFFFFE000u);
        ls[j] = xs[j] - hs[j];
    }
    #pragma unroll
    for (int j = 0; j < 4; ++j) {
        const h16x2 ph = __builtin_amdgcn_cvt_pkrtz(hs[2 * j], hs[2 * j + 1]);
        const h16x2 pl = __builtin_amdgcn_cvt_pkrtz(ls[2 * j], ls[2 * j + 1]);
        hi[2 * j] = (_Float16)ph[0]; hi[2 * j + 1] = (_Float16)ph[1];
        lo[2 * j] = (_Float16)pl[0]; lo[2 * j + 1] = (_Float16)pl[1];
    }
}

// ---------------------------------------------------------------------------
// K1: split-K=4 GEMM, BM=64, single barrier per iteration. (Best-measured
// configuration: r15, 78.1 µs; re-verified r19, 79.9 µs.)
// grid (256, 4): bx = 64-row tile, by = k-quarter.
// Wave (wm,we): rows {wm*16..+16, 32+wm*16..+16} x experts we*32..+32;
// B frags read once, reused by both m-frags (12 MFMA/iter).
// Hazard audit for 1 barrier/iter:
//   RAW tile i+1: every wave's WAITV(2) (forces A(i+1)+B(i+1)) + end barrier.
//   WAR aStg (written iter i, last ds_read at iter i-1): end barrier of i-1
//     precedes the gll issue (a gll write cannot land before issue).
// ---------------------------------------------------------------------------
__global__ __launch_bounds__(256, 4) void gemm_q_kernel(
    const float* __restrict__ h, const _Float16* __restrict__ Wt,
    float* __restrict__ out)
{
    __shared__ char smb[LDS_TOT];

    const int tid  = threadIdx.x;
    const int wv   = tid >> 6;
    const int lane = tid & 63;
    const int l15  = lane & 15;
    const int kg   = lane >> 4;          // 0..3
    const int wm   = wv >> 1;            // m-quarter (within each 32-row half)
    const int we   = wv & 1;             // e-half
    const int row0 = blockIdx.x * BM;
    const int q    = blockIdx.y;         // k-quarter
    const int kb   = q * KQ;

    // ---- A staging: wave stages rows wv*16..+15 via 2 glls (8 rows each).
    // Lane: row p*8 + (lane>>3), chunk slot lane&7; source chunk pre-swizzled
    // (lane&7) ^ (row&7) so LDS(r,c') = G(r, c' ^ (r&7)); dest linear.
    const char* gA[2]; int lA[2];
    #pragma unroll
    for (int p = 0; p < 2; ++p) {
        const int row = wv * 16 + p * 8 + (lane >> 3);
        gA[p] = (const char*)h + ((size_t)(row0 + row) * D_DIM + kb) * 4
                + (((lane & 7) ^ (lane >> 3)) << 4);
        lA[p] = wv * 2048 + p * 1024;
    }
    // ---- B staging: 2 glls/wave, linear copy of pre-swizzled 8KB tiles.
    // Quarter q's tiles start at tile q*32 -> byte offset q*32*8192.
    const char* gB = (const char*)Wt + (size_t)(q * 32) * 8192
                     + wv * 2048 + lane * 16;
    const int lB = wv * 2048;            // + B_OFF + par*BBUF at use

    // ---- A ds_read offsets: m-frag f -> row f*32 + wm*16 + l15 ----
    int aro[2][2];                       // [f][piece]
    #pragma unroll
    for (int f = 0; f < 2; ++f)
        #pragma unroll
        for (int qq = 0; qq < 2; ++qq)
            aro[f][qq] = (f * 32 + wm * 16 + l15) * 128
                       + (((kg * 2 + qq) ^ (l15 & 7)) << 4);
    // ---- B ds_read offsets: expert e, chunk kg ^ (e&3) ----
    int bro[2][2];                       // [sel hi/lo][es]
    #pragma unroll
    for (int sel = 0; sel < 2; ++sel)
        #pragma unroll
        for (int es = 0; es < 2; ++es) {
            const int e = we * 32 + es * 16 + l15;
            bro[sel][es] = sel * 4096 + e * 64 + ((kg ^ (e & 3)) << 4);
        }

    f32x4 acc[2][2] = {};                // [f][es]
    float4 av[2][2];                     // [f][piece]
    f16x8 bhf[2], blf[2];                // [es]

    int aCur = 0, aNxt = ABUF, aStg = 2 * ABUF;

    #define STAGE_A(t, aAdd)                                          \
        { _Pragma("unroll")                                           \
          for (int p = 0; p < 2; ++p)                                 \
              gll16(gA[p] + (size_t)(t) * 128, smb + (aAdd) + lA[p]); }
    #define STAGE_B(t, par)                                           \
        { gll16(gB + (size_t)(t) * 8192,        smb + B_OFF + (par) * BBUF + lB); \
          gll16(gB + (size_t)(t) * 8192 + 1024, smb + B_OFF + (par) * BBUF + lB + 1024); }

    #define DSREAD(aAdd, par)                                                 \
        { _Pragma("unroll")                                                   \
          for (int f = 0; f < 2; ++f) {                                       \
              av[f][0] = *(const float4*)(smb + (aAdd) + aro[f][0]);          \
              av[f][1] = *(const float4*)(smb + (aAdd) + aro[f][1]);          \
          }                                                                   \
          _Pragma("unroll")                                                   \
          for (int es = 0; es < 2; ++es) {                                    \
              bhf[es] = *(const f16x8*)(smb + B_OFF + (par) * BBUF + bro[0][es]); \
              blf[es] = *(const f16x8*)(smb + B_OFF + (par) * BBUF + bro[1][es]); \
          } }

    #define MFMAS()                                                           \
        { f16x8 ah[2], al[2];                                                 \
          cvt8(av[0][0], av[0][1], ah[0], al[0]);                             \
          cvt8(av[1][0], av[1][1], ah[1], al[1]);                             \
          _Pragma("unroll")                                                   \
          for (int f = 0; f < 2; ++f)                                         \
              _Pragma("unroll")                                               \
              for (int es = 0; es < 2; ++es) {                                \
                  acc[f][es] = __builtin_amdgcn_mfma_f32_16x16x32_f16(ah[f], bhf[es], acc[f][es], 0, 0, 0); \
                  acc[f][es] = __builtin_amdgcn_mfma_f32_16x16x32_f16(ah[f], blf[es], acc[f][es], 0, 0, 0); \
                  acc[f][es] = __builtin_amdgcn_mfma_f32_16x16x32_f16(al[f], bhf[es], acc[f][es], 0, 0, 0); \
              } }

    #define ROT() { int t_ = aCur; aCur = aNxt; aNxt = aStg; aStg = t_; }

    // prologue: FIFO [A0(2) | B0(2) | A1(2)]; WAITV(2) leaves A1, forces A0+B0.
    STAGE_A(0, aCur)
    SB0();
    STAGE_B(0, 0)
    SB0();
    STAGE_A(1, aNxt)
    SB0();
    WAITV(2);
    SB0();
    __builtin_amdgcn_s_barrier();

    // main loop: ONE barrier per iteration.
    // Invariant entering iter i: only A(i+1)'s 2 glls outstanding.
    // Issue B(i+1), fence, A(i+2); MFMA(i); WAITV(2) forces A(i+1)+B(i+1),
    // leaves A(i+2) in flight across the barrier.
    for (int i = 0; i < NIT - 2; ++i) {
        DSREAD(aCur, i & 1)
        STAGE_B(i + 1, (i + 1) & 1)
        SB0();                           // pin FIFO order: B(i+1) before A(i+2)
        STAGE_A(i + 2, aStg)
        SB0();
        __builtin_amdgcn_s_setprio(1);
        MFMAS()
        __builtin_amdgcn_s_setprio(0);
        WAITV(2);
        SB0();
        __builtin_amdgcn_s_barrier();
        ROT();
    }
    // tail: tiles NIT-2, NIT-1
    DSREAD(aCur, (NIT - 2) & 1)
    STAGE_B(NIT - 1, (NIT - 1) & 1)
    SB0();
    MFMAS()
    WAITV(0);
    SB0();
    __builtin_amdgcn_s_barrier();
    ROT();
    DSREAD(aCur, (NIT - 1) & 1)
    MFMAS()

    // ---- write scaled partials to out slot q ----
    float* slot = out + (size_t)q * T_ROWS * E_EXP;
    #pragma unroll
    for (int f = 0; f < 2; ++f)
        #pragma unroll
        for (int es = 0; es < 2; ++es)
            #pragma unroll
            for (int r = 0; r < 4; ++r)
                slot[(size_t)(row0 + f * 32 + wm * 16 + kg * 4 + r) * E_EXP
                     + we * 32 + es * 16 + l15] = acc[f][es][r];
}

// ---------------------------------------------------------------------------
// K2: elementwise-safe epilogue. Each thread reads its 4 quarter-partials
// from the 4 out slots, then overwrites the same 4 addresses with
// mask / probs / logits_clean / logits_sel. One wave per row, lane = expert.
// ---------------------------------------------------------------------------
__global__ __launch_bounds__(256) void epilogue_kernel(
    const float* __restrict__ u, float* __restrict__ out)
{
    const int row  = blockIdx.x * 4 + (threadIdx.x >> 6);
    const int lane = threadIdx.x & 63;
    const size_t te = (size_t)T_ROWS * E_EXP;
    const size_t idx = (size_t)row * E_EXP + lane;

    const float p0 = out[0 * te + idx];
    const float p1 = out[1 * te + idx];
    const float p2 = out[2 * te + idx];
    const float p3 = out[3 * te + idx];
    const float val = (((p0 + p1) + p2) + p3) * INV_SCALE;

    out[2 * te + idx] = val;             // logits_clean

    float m = val;
    #pragma unroll
    for (int off = 32; off; off >>= 1) m = fmaxf(m, __shfl_xor(m, off));
    const float p = expf(val - m);
    float ssum = p;
    #pragma unroll
    for (int off = 32; off; off >>= 1) ssum += __shfl_xor(ssum, off);
    out[1 * te + idx] = p / ssum;        // probs

    const float uv = u[idx];
    const float g = -logf(-logf(uv));
    const float sel = val + g;
    out[3 * te + idx] = sel;             // logits_sel

    // top-8, ties -> lowest lane (= lowest expert, matches lax.top_k)
    float v = sel;
    bool chosen = false;
    #pragma unroll
    for (int itk = 0; itk < TOPK; ++itk) {
        float mv = v;
        #pragma unroll
        for (int off = 32; off; off >>= 1) mv = fmaxf(mv, __shfl_xor(mv, off));
        const unsigned long long b = __ballot(v == mv);
        const int sl = __ffsll((long long)b) - 1;
        if (lane == sl) { chosen = true; v = -INFINITY; }
    }
    out[idx] = chosen ? 1.0f : 0.0f;     // mask
}

// ---------------------------------------------------------------------------
extern "C" void kernel_launch(void* const* d_in, const int* in_sizes, int n_in,
                              void* d_out, int out_size, void* d_ws, size_t ws_size,
                              hipStream_t stream) {
    const float* h = (const float*)d_in[0];
    const float* W = (const float*)d_in[1];
    const float* u = (const float*)d_in[2];
    float* out = (float*)d_out;

    _Float16* Wt = (_Float16*)d_ws;                        // 1 MB packed tiles

    hipLaunchKernelGGL(wprep_kernel, dim3(E_EXP * D_DIM / 8 / 256), dim3(256),
                       0, stream, W, Wt);
    hipLaunchKernelGGL(gemm_q_kernel, dim3(T_ROWS / BM, 4), dim3(256),
                       0, stream, h, Wt, out);
    hipLaunchKernelGGL(epilogue_kernel, dim3(T_ROWS / 4), dim3(256),
                       0, stream, u, out);
}